// Round 1
// baseline (586.684 us; speedup 1.0000x reference)
//
#include <hip/hip_runtime.h>
#include <hip/hip_cooperative_groups.h>
#include <math.h>

// MinGRU: B=8, S=8192, D=256, H=256, fp32 in/out.
//   K1 gemm_zh    : bf16-MFMA dual GEMM (z,h) + sigmoid epilogue (unchanged).
//   K2 scan_fused : cooperative kernel; phaseA (chunk P,Q) -> grid.sync ->
//                   phaseB (8 blocks, sequential over chunk summaries) ->
//                   grid.sync -> phaseC replay FROM REGISTERS (ab loaded once).
//                   Eliminates the 64 MiB ab re-read + 2 kernel launches.
//   Fallback: original 3-kernel path if cooperative launch is rejected.

constexpr int B_ = 8;
constexpr int S_ = 8192;
constexpr int D_ = 256;
constexpr int H_ = 256;
constexpr int M_ = B_ * S_;        // 65536 rows
constexpr int CHUNKS = 128;
constexpr int CLEN = S_ / CHUNKS;  // 64

typedef __attribute__((ext_vector_type(8))) short bf16x8;
typedef __attribute__((ext_vector_type(4))) float f32x4;

// 2 floats -> 2 bf16 (round-to-nearest, ties-away): 2 adds + 1 v_perm.
// lo16 = bf16(f0), hi16 = bf16(f1).
__device__ __forceinline__ uint pack2bf(float f0, float f1) {
  const uint u0 = __float_as_uint(f0) + 0x8000u;
  const uint u1 = __float_as_uint(f1) + 0x8000u;
  return __builtin_amdgcn_perm(u1, u0, 0x07060302u);
}

// ---------------------------------------------------------------- GEMM ----
// Block: 256 thr = 4 waves. Tile: 128 rows x 64 h-channels, both projections.
// LDS rows padded to 72 bf16: conflict-free b128 fragment reads.
__global__ __launch_bounds__(256) void gemm_zh(
    const float* __restrict__ x,
    const float* __restrict__ whw, const float* __restrict__ whb,
    const float* __restrict__ wzw, const float* __restrict__ wzb,
    uint* __restrict__ ab)
{
  __shared__ ushort xs[128][72];
  __shared__ ushort wzs[64][72];
  __shared__ ushort whs[64][72];

  const int tid = threadIdx.x;
  // XCD swizzle: one 128-row x-panel per XCD group -> x L2-local.
  const int g    = blockIdx.x;
  const int xcd  = g & 7;
  const int loc  = g >> 3;
  const int nt   = loc & 3;
  const int panel = (loc >> 2) * 8 + xcd;
  const int m0 = panel * 128;
  const int n0 = nt * 64;

  const int lane = tid & 63;
  const int w  = tid >> 6;
  const int mb = (w & 1) * 64;
  const int nb = (w >> 1) * 32;
  const int q  = lane >> 4;
  const int cn = lane & 15;

  f32x4 accz[4][2] = {};
  f32x4 acch[4][2] = {};

  for (int k0 = 0; k0 < D_; k0 += 64) {
    __syncthreads();  // WAR guard on LDS reuse
#pragma unroll
    for (int f = 0; f < 8; f++) {  // x: 128 rows x 64 k
      const int idx = tid + 256 * f;
      const int row = idx >> 4, seg = idx & 15;
      float4 v = *(const float4*)(x + (size_t)(m0 + row) * D_ + k0 + seg * 4);
      *(uint2*)&xs[row][seg * 4] =
          make_uint2(pack2bf(v.x, v.y), pack2bf(v.z, v.w));
    }
#pragma unroll
    for (int f = 0; f < 4; f++) {  // weights: 64 rows x 64 k each
      const int idx = tid + 256 * f;
      const int row = idx >> 4, seg = idx & 15;
      float4 vz = *(const float4*)(wzw + (size_t)(n0 + row) * D_ + k0 + seg * 4);
      float4 vh = *(const float4*)(whw + (size_t)(n0 + row) * D_ + k0 + seg * 4);
      *(uint2*)&wzs[row][seg * 4] =
          make_uint2(pack2bf(vz.x, vz.y), pack2bf(vz.z, vz.w));
      *(uint2*)&whs[row][seg * 4] =
          make_uint2(pack2bf(vh.x, vh.y), pack2bf(vh.z, vh.w));
    }
    __syncthreads();
#pragma unroll
    for (int ks = 0; ks < 2; ks++) {
      const int kk = ks * 32 + q * 8;  // A[m=lane&15][k=quad*8+j]
      bf16x8 af[4], bz[2], bh[2];
#pragma unroll
      for (int i = 0; i < 4; i++)
        af[i] = *(const bf16x8*)&xs[mb + i * 16 + cn][kk];
#pragma unroll
      for (int j = 0; j < 2; j++) {
        bz[j] = *(const bf16x8*)&wzs[nb + j * 16 + cn][kk];
        bh[j] = *(const bf16x8*)&whs[nb + j * 16 + cn][kk];
      }
#pragma unroll
      for (int i = 0; i < 4; i++)
#pragma unroll
        for (int j = 0; j < 2; j++) {
          accz[i][j] = __builtin_amdgcn_mfma_f32_16x16x32_bf16(af[i], bz[j], accz[i][j], 0, 0, 0);
          acch[i][j] = __builtin_amdgcn_mfma_f32_16x16x32_bf16(af[i], bh[j], acch[i][j], 0, 0, 0);
        }
    }
  }

  // Epilogue: C/D col=lane&15, row=quad*4+reg. a=e*rcp, b=h~*rcp.
#pragma unroll
  for (int j = 0; j < 2; j++) {
    const int ch = n0 + nb + j * 16 + cn;
    const float zb = wzb[ch], hb = whb[ch];
#pragma unroll
    for (int i = 0; i < 4; i++) {
#pragma unroll
      for (int r = 0; r < 4; r++) {
        const int row = m0 + mb + i * 16 + q * 4 + r;
        const float zpre = accz[i][j][r] + zb;
        const float hpre = acch[i][j][r] + hb;
        const float e = __expf(-zpre);
        const float rcp = __builtin_amdgcn_rcpf(1.0f + e);  // z
        ab[(size_t)row * H_ + ch] = pack2bf(e * rcp, hpre * rcp);
      }
    }
  }
}

// ------------------------------------------------------- fused scan ------
// 1024 blocks (b = blk>>7, c = blk&127), 256 thr = 1 channel each.
// Registers hold the chunk's 64 packed ab values across both grid syncs,
// so ab is read exactly once. __launch_bounds__(256,4) caps VGPR at 128
// (v[64] + ~30 others) -> 4 blocks/CU -> exactly 1024 co-resident blocks.
__global__ __launch_bounds__(256, 4) void scan_fused(
    const uint* __restrict__ ab, const float* __restrict__ h0in,
    float* __restrict__ chunkP, float* __restrict__ chunkQ,
    float* __restrict__ hstate, float* __restrict__ out)
{
  const int blk = blockIdx.x;
  const int b = blk >> 7;
  const int c = blk & (CHUNKS - 1);
  const int ch = threadIdx.x;
  const size_t base = ((size_t)b * S_ + (size_t)c * CLEN) * H_ + ch;
  const size_t cidx = ((size_t)b * CHUNKS + c) * H_ + ch;

  // ---- phase A: load chunk once (64 outstanding dword loads), (P,Q) ----
  uint v[CLEN];
#pragma unroll
  for (int t = 0; t < CLEN; t++)
    v[t] = ab[base + (size_t)t * H_];

  float P = 1.f, Q = 0.f;
#pragma unroll
  for (int t = 0; t < CLEN; t++) {
    const float a  = __uint_as_float(v[t] << 16);
    const float bb = __uint_as_float(v[t] & 0xFFFF0000u);
    Q = fmaf(a, Q, bb);
    P *= a;
  }
  chunkP[cidx] = P;
  chunkQ[cidx] = Q;

  __threadfence();  // release chunk summaries device-wide
  cooperative_groups::this_grid().sync();

  // ---- phase B: 8 blocks (one per batch) scan the chunk summaries ----
  if (blk < B_) {
    const int b2 = blk;
    const size_t base2 = (size_t)b2 * CHUNKS * H_ + ch;
    float hc = h0in[(size_t)b2 * H_ + ch];
    for (int c0 = 0; c0 < CHUNKS; c0 += 8) {
      float p[8], q[8];
#pragma unroll
      for (int j = 0; j < 8; j++) {
        p[j] = chunkP[base2 + (size_t)(c0 + j) * H_];
        q[j] = chunkQ[base2 + (size_t)(c0 + j) * H_];
      }
#pragma unroll
      for (int j = 0; j < 8; j++) {
        hstate[base2 + (size_t)(c0 + j) * H_] = hc;
        hc = fmaf(p[j], hc, q[j]);
      }
    }
  }

  __threadfence();  // release hstate device-wide
  cooperative_groups::this_grid().sync();

  // ---- phase C: replay from registers, write output ----
  float hc = hstate[cidx];
#pragma unroll
  for (int t = 0; t < CLEN; t++) {
    const float a  = __uint_as_float(v[t] << 16);
    const float bb = __uint_as_float(v[t] & 0xFFFF0000u);
    hc = fmaf(a, hc, bb);
    out[base + (size_t)t * H_] = hc;
  }
}

// ------------------------------------------------- fallback (3-kernel) ---
__global__ __launch_bounds__(256) void scan_phaseA(
    const uint* __restrict__ ab,
    float* __restrict__ P_out, float* __restrict__ Q_out)
{
  const int c = blockIdx.x;
  const int b = blockIdx.y;
  const int ch = threadIdx.x;
  size_t base = ((size_t)b * S_ + (size_t)c * CLEN) * H_ + ch;
  float P = 1.f, Q = 0.f;
  for (int t0 = 0; t0 < CLEN; t0 += 8) {
    uint v[8];
#pragma unroll
    for (int j = 0; j < 8; j++)
      v[j] = ab[base + (size_t)(t0 + j) * H_];
#pragma unroll
    for (int j = 0; j < 8; j++) {
      const float a = __uint_as_float(v[j] << 16);
      const float bb = __uint_as_float(v[j] & 0xFFFF0000u);
      Q = fmaf(a, Q, bb);
      P *= a;
    }
  }
  const size_t idx = ((size_t)b * CHUNKS + c) * H_ + ch;
  P_out[idx] = P;
  Q_out[idx] = Q;
}

__global__ __launch_bounds__(256) void scan_phaseB(
    const float* __restrict__ h0in, const float* __restrict__ P,
    const float* __restrict__ Q, float* __restrict__ hstate)
{
  const int b = blockIdx.x;
  const int h = threadIdx.x;
  const size_t base = (size_t)b * CHUNKS * H_ + h;
  float hc = h0in[(size_t)b * H_ + h];
  for (int c0 = 0; c0 < CHUNKS; c0 += 8) {
    float p[8], q[8];
#pragma unroll
    for (int j = 0; j < 8; j++) {
      p[j] = P[base + (size_t)(c0 + j) * H_];
      q[j] = Q[base + (size_t)(c0 + j) * H_];
    }
#pragma unroll
    for (int j = 0; j < 8; j++) {
      hstate[base + (size_t)(c0 + j) * H_] = hc;
      hc = fmaf(p[j], hc, q[j]);
    }
  }
}

__global__ __launch_bounds__(256) void scan_phaseC(
    const uint* __restrict__ ab, const float* __restrict__ hstate,
    float* __restrict__ out)
{
  const int c = blockIdx.x;
  const int b = blockIdx.y;
  const int ch = threadIdx.x;
  size_t base = ((size_t)b * S_ + (size_t)c * CLEN) * H_ + ch;
  float hc = hstate[((size_t)b * CHUNKS + c) * H_ + ch];
  for (int t0 = 0; t0 < CLEN; t0 += 8) {
    uint v[8];
#pragma unroll
    for (int j = 0; j < 8; j++)
      v[j] = ab[base + (size_t)(t0 + j) * H_];
#pragma unroll
    for (int j = 0; j < 8; j++) {
      const float a = __uint_as_float(v[j] << 16);
      const float bb = __uint_as_float(v[j] & 0xFFFF0000u);
      hc = fmaf(a, hc, bb);
      out[base + (size_t)(t0 + j) * H_] = hc;
    }
  }
}

extern "C" void kernel_launch(void* const* d_in, const int* in_sizes, int n_in,
                              void* d_out, int out_size, void* d_ws, size_t ws_size,
                              hipStream_t stream) {
  const float* x   = (const float*)d_in[0];
  const float* h0  = (const float*)d_in[1];
  const float* whw = (const float*)d_in[2];
  const float* whb = (const float*)d_in[3];
  const float* wzw = (const float*)d_in[4];
  const float* wzb = (const float*)d_in[5];
  float* out = (float*)d_out;

  uint*  ab     = (uint*)d_ws;                        // [M,H] packed bf16 {b,a}
  float* chunkP = (float*)(ab + (size_t)M_ * H_);     // [B,CHUNKS,H]
  float* chunkQ = chunkP + (size_t)B_ * CHUNKS * H_;  // [B,CHUNKS,H]
  float* hstate = chunkQ + (size_t)B_ * CHUNKS * H_;  // [B,CHUNKS,H]

  gemm_zh<<<(M_ / 128) * 4, 256, 0, stream>>>(x, whw, whb, wzw, wzb, ab);

  const uint* ab_c = ab;
  void* cargs[6] = {(void*)&ab_c, (void*)&h0, (void*)&chunkP,
                    (void*)&chunkQ, (void*)&hstate, (void*)&out};
  hipError_t err = hipLaunchCooperativeKernel(
      scan_fused, dim3(CHUNKS * B_), dim3(256), cargs, 0, stream);
  if (err != hipSuccess) {
    // Fallback: original 3-kernel scan path.
    scan_phaseA<<<dim3(CHUNKS, B_), 256, 0, stream>>>(ab, chunkP, chunkQ);
    scan_phaseB<<<B_, 256, 0, stream>>>(h0, chunkP, chunkQ, hstate);
    scan_phaseC<<<dim3(CHUNKS, B_), 256, 0, stream>>>(ab, hstate, out);
  }
}

// Round 2
// 566.925 us; speedup vs baseline: 1.0349x; 1.0349x over previous
//
#include <hip/hip_runtime.h>
#include <math.h>

// MinGRU: B=8, S=8192, D=256, H=256, fp32 in/out.
//   K1 gemm_zh    : bf16-MFMA dual GEMM (z,h) + sigmoid epilogue (unchanged).
//   K2 scan_fused : cooperative-launched kernel with INLINE grid barrier
//                   (manual agent-scope atomics; cooperative_groups'
//                   __ockl_grid_sync call forced a 64-VGPR spill of v[] to
//                   scratch in R1 -> 414us. Inline sync keeps v[] in regs.)
//                   phaseA (chunk P,Q; ab -> 64 regs) -> gsync ->
//                   phaseB (8 blocks scan chunk summaries) -> gsync ->
//                   phaseC replay FROM REGISTERS. ab read exactly once.
//   Fallback: original 3-kernel path if ws too small or coop launch rejected.

constexpr int B_ = 8;
constexpr int S_ = 8192;
constexpr int D_ = 256;
constexpr int H_ = 256;
constexpr int M_ = B_ * S_;        // 65536 rows
constexpr int CHUNKS = 128;
constexpr int CLEN = S_ / CHUNKS;  // 64
constexpr int GRID_FUSED = CHUNKS * B_;  // 1024 = 4 blocks/CU x 256 CU

typedef __attribute__((ext_vector_type(8))) short bf16x8;
typedef __attribute__((ext_vector_type(4))) float f32x4;

// 2 floats -> 2 bf16 (round-to-nearest, ties-away): 2 adds + 1 v_perm.
// lo16 = bf16(f0), hi16 = bf16(f1).
__device__ __forceinline__ uint pack2bf(float f0, float f1) {
  const uint u0 = __float_as_uint(f0) + 0x8000u;
  const uint u1 = __float_as_uint(f1) + 0x8000u;
  return __builtin_amdgcn_perm(u1, u0, 0x07060302u);
}

// ---------------------------------------------------------------- GEMM ----
// Block: 256 thr = 4 waves. Tile: 128 rows x 64 h-channels, both projections.
// LDS rows padded to 72 bf16: conflict-free b128 fragment reads.
__global__ __launch_bounds__(256) void gemm_zh(
    const float* __restrict__ x,
    const float* __restrict__ whw, const float* __restrict__ whb,
    const float* __restrict__ wzw, const float* __restrict__ wzb,
    uint* __restrict__ ab)
{
  __shared__ ushort xs[128][72];
  __shared__ ushort wzs[64][72];
  __shared__ ushort whs[64][72];

  const int tid = threadIdx.x;
  // XCD swizzle: one 128-row x-panel per XCD group -> x L2-local.
  const int g    = blockIdx.x;
  const int xcd  = g & 7;
  const int loc  = g >> 3;
  const int nt   = loc & 3;
  const int panel = (loc >> 2) * 8 + xcd;
  const int m0 = panel * 128;
  const int n0 = nt * 64;

  const int lane = tid & 63;
  const int w  = tid >> 6;
  const int mb = (w & 1) * 64;
  const int nb = (w >> 1) * 32;
  const int q  = lane >> 4;
  const int cn = lane & 15;

  f32x4 accz[4][2] = {};
  f32x4 acch[4][2] = {};

  for (int k0 = 0; k0 < D_; k0 += 64) {
    __syncthreads();  // WAR guard on LDS reuse
#pragma unroll
    for (int f = 0; f < 8; f++) {  // x: 128 rows x 64 k
      const int idx = tid + 256 * f;
      const int row = idx >> 4, seg = idx & 15;
      float4 v = *(const float4*)(x + (size_t)(m0 + row) * D_ + k0 + seg * 4);
      *(uint2*)&xs[row][seg * 4] =
          make_uint2(pack2bf(v.x, v.y), pack2bf(v.z, v.w));
    }
#pragma unroll
    for (int f = 0; f < 4; f++) {  // weights: 64 rows x 64 k each
      const int idx = tid + 256 * f;
      const int row = idx >> 4, seg = idx & 15;
      float4 vz = *(const float4*)(wzw + (size_t)(n0 + row) * D_ + k0 + seg * 4);
      float4 vh = *(const float4*)(whw + (size_t)(n0 + row) * D_ + k0 + seg * 4);
      *(uint2*)&wzs[row][seg * 4] =
          make_uint2(pack2bf(vz.x, vz.y), pack2bf(vz.z, vz.w));
      *(uint2*)&whs[row][seg * 4] =
          make_uint2(pack2bf(vh.x, vh.y), pack2bf(vh.z, vh.w));
    }
    __syncthreads();
#pragma unroll
    for (int ks = 0; ks < 2; ks++) {
      const int kk = ks * 32 + q * 8;  // A[m=lane&15][k=quad*8+j]
      bf16x8 af[4], bz[2], bh[2];
#pragma unroll
      for (int i = 0; i < 4; i++)
        af[i] = *(const bf16x8*)&xs[mb + i * 16 + cn][kk];
#pragma unroll
      for (int j = 0; j < 2; j++) {
        bz[j] = *(const bf16x8*)&wzs[nb + j * 16 + cn][kk];
        bh[j] = *(const bf16x8*)&whs[nb + j * 16 + cn][kk];
      }
#pragma unroll
      for (int i = 0; i < 4; i++)
#pragma unroll
        for (int j = 0; j < 2; j++) {
          accz[i][j] = __builtin_amdgcn_mfma_f32_16x16x32_bf16(af[i], bz[j], accz[i][j], 0, 0, 0);
          acch[i][j] = __builtin_amdgcn_mfma_f32_16x16x32_bf16(af[i], bh[j], acch[i][j], 0, 0, 0);
        }
    }
  }

  // Epilogue: C/D col=lane&15, row=quad*4+reg. a=e*rcp, b=h~*rcp.
#pragma unroll
  for (int j = 0; j < 2; j++) {
    const int ch = n0 + nb + j * 16 + cn;
    const float zb = wzb[ch], hb = whb[ch];
#pragma unroll
    for (int i = 0; i < 4; i++) {
#pragma unroll
      for (int r = 0; r < 4; r++) {
        const int row = m0 + mb + i * 16 + q * 4 + r;
        const float zpre = accz[i][j][r] + zb;
        const float hpre = acch[i][j][r] + hb;
        const float e = __expf(-zpre);
        const float rcp = __builtin_amdgcn_rcpf(1.0f + e);  // z
        ab[(size_t)row * H_ + ch] = pack2bf(e * rcp, hpre * rcp);
      }
    }
  }
}

// ------------------------------------------------------- fused scan ------
// Inline grid barrier: single counter, cumulative targets (1024, 2048).
// ACQ_REL agent-scope RMW = release (L2 writeback to LLC); ACQUIRE agent
// spin-load = acquire (cache inv). No function call -> v[] stays in VGPRs.
__device__ __forceinline__ void gsync(uint* bar, uint target) {
  __syncthreads();
  if (threadIdx.x == 0) {
    __hip_atomic_fetch_add(bar, 1u, __ATOMIC_ACQ_REL, __HIP_MEMORY_SCOPE_AGENT);
    while (__hip_atomic_load(bar, __ATOMIC_ACQUIRE, __HIP_MEMORY_SCOPE_AGENT)
           < target)
      __builtin_amdgcn_s_sleep(1);
  }
  __syncthreads();
}

// Coherent (agent-scope, LLC) load of cross-XCD-written f32.
__device__ __forceinline__ float cohload(const float* p) {
  return __hip_atomic_load(p, __ATOMIC_RELAXED, __HIP_MEMORY_SCOPE_AGENT);
}

// 1024 blocks (b = blk>>7, c = blk&127), 256 thr = 1 channel each.
// v[64] (the chunk's packed ab) stays live across both syncs, so ab is
// read exactly once. __launch_bounds__(256,4) -> VGPR cap 128 (need ~100)
// -> 4 blocks/CU -> exactly 1024 co-resident blocks (coop launch verifies).
__global__ __launch_bounds__(256, 4) void scan_fused(
    const uint* __restrict__ ab, const float* __restrict__ h0in,
    float* __restrict__ chunkP, float* __restrict__ chunkQ,
    float* __restrict__ hstate, float* __restrict__ out,
    uint* __restrict__ bar)
{
  const int blk = blockIdx.x;
  const int b = blk >> 7;
  const int c = blk & (CHUNKS - 1);
  const int ch = threadIdx.x;
  const size_t base = ((size_t)b * S_ + (size_t)c * CLEN) * H_ + ch;
  const size_t cidx = ((size_t)b * CHUNKS + c) * H_ + ch;

  // ---- phase A: load chunk once (stays in regs), compute (P,Q) ----
  uint v[CLEN];
#pragma unroll
  for (int t = 0; t < CLEN; t++)
    v[t] = ab[base + (size_t)t * H_];

  float P = 1.f, Q = 0.f;
#pragma unroll
  for (int t = 0; t < CLEN; t++) {
    const float a  = __uint_as_float(v[t] << 16);
    const float bb = __uint_as_float(v[t] & 0xFFFF0000u);
    Q = fmaf(a, Q, bb);
    P *= a;
  }
  chunkP[cidx] = P;
  chunkQ[cidx] = Q;

  gsync(bar, GRID_FUSED);

  // ---- phase B: 8 blocks (one per batch) scan the chunk summaries ----
  if (blk < B_) {
    const int b2 = blk;
    const size_t base2 = (size_t)b2 * CHUNKS * H_ + ch;
    float hc = h0in[(size_t)b2 * H_ + ch];
    for (int c0 = 0; c0 < CHUNKS; c0 += 8) {
      float p[8], q[8];
#pragma unroll
      for (int j = 0; j < 8; j++) {
        p[j] = cohload(&chunkP[base2 + (size_t)(c0 + j) * H_]);
        q[j] = cohload(&chunkQ[base2 + (size_t)(c0 + j) * H_]);
      }
#pragma unroll
      for (int j = 0; j < 8; j++) {
        hstate[base2 + (size_t)(c0 + j) * H_] = hc;
        hc = fmaf(p[j], hc, q[j]);
      }
    }
  }

  gsync(bar, 2 * GRID_FUSED);

  // ---- phase C: replay from registers, write output ----
  float hc = cohload(&hstate[cidx]);
#pragma unroll
  for (int t = 0; t < CLEN; t++) {
    const float a  = __uint_as_float(v[t] << 16);
    const float bb = __uint_as_float(v[t] & 0xFFFF0000u);
    hc = fmaf(a, hc, bb);
    out[base + (size_t)t * H_] = hc;
  }
}

// ------------------------------------------------- fallback (3-kernel) ---
__global__ __launch_bounds__(256) void scan_phaseA(
    const uint* __restrict__ ab,
    float* __restrict__ P_out, float* __restrict__ Q_out)
{
  const int c = blockIdx.x;
  const int b = blockIdx.y;
  const int ch = threadIdx.x;
  size_t base = ((size_t)b * S_ + (size_t)c * CLEN) * H_ + ch;
  float P = 1.f, Q = 0.f;
  for (int t0 = 0; t0 < CLEN; t0 += 8) {
    uint v[8];
#pragma unroll
    for (int j = 0; j < 8; j++)
      v[j] = ab[base + (size_t)(t0 + j) * H_];
#pragma unroll
    for (int j = 0; j < 8; j++) {
      const float a = __uint_as_float(v[j] << 16);
      const float bb = __uint_as_float(v[j] & 0xFFFF0000u);
      Q = fmaf(a, Q, bb);
      P *= a;
    }
  }
  const size_t idx = ((size_t)b * CHUNKS + c) * H_ + ch;
  P_out[idx] = P;
  Q_out[idx] = Q;
}

__global__ __launch_bounds__(256) void scan_phaseB(
    const float* __restrict__ h0in, const float* __restrict__ P,
    const float* __restrict__ Q, float* __restrict__ hstate)
{
  const int b = blockIdx.x;
  const int h = threadIdx.x;
  const size_t base = (size_t)b * CHUNKS * H_ + h;
  float hc = h0in[(size_t)b * H_ + h];
  for (int c0 = 0; c0 < CHUNKS; c0 += 8) {
    float p[8], q[8];
#pragma unroll
    for (int j = 0; j < 8; j++) {
      p[j] = P[base + (size_t)(c0 + j) * H_];
      q[j] = Q[base + (size_t)(c0 + j) * H_];
    }
#pragma unroll
    for (int j = 0; j < 8; j++) {
      hstate[base + (size_t)(c0 + j) * H_] = hc;
      hc = fmaf(p[j], hc, q[j]);
    }
  }
}

__global__ __launch_bounds__(256) void scan_phaseC(
    const uint* __restrict__ ab, const float* __restrict__ hstate,
    float* __restrict__ out)
{
  const int c = blockIdx.x;
  const int b = blockIdx.y;
  const int ch = threadIdx.x;
  size_t base = ((size_t)b * S_ + (size_t)c * CLEN) * H_ + ch;
  float hc = hstate[((size_t)b * CHUNKS + c) * H_ + ch];
  for (int t0 = 0; t0 < CLEN; t0 += 8) {
    uint v[8];
#pragma unroll
    for (int j = 0; j < 8; j++)
      v[j] = ab[base + (size_t)(t0 + j) * H_];
#pragma unroll
    for (int j = 0; j < 8; j++) {
      const float a = __uint_as_float(v[j] << 16);
      const float bb = __uint_as_float(v[j] & 0xFFFF0000u);
      hc = fmaf(a, hc, bb);
      out[base + (size_t)(t0 + j) * H_] = hc;
    }
  }
}

extern "C" void kernel_launch(void* const* d_in, const int* in_sizes, int n_in,
                              void* d_out, int out_size, void* d_ws, size_t ws_size,
                              hipStream_t stream) {
  const float* x   = (const float*)d_in[0];
  const float* h0  = (const float*)d_in[1];
  const float* whw = (const float*)d_in[2];
  const float* whb = (const float*)d_in[3];
  const float* wzw = (const float*)d_in[4];
  const float* wzb = (const float*)d_in[5];
  float* out = (float*)d_out;

  uint*  ab     = (uint*)d_ws;                        // [M,H] packed bf16 {b,a}
  float* chunkP = (float*)(ab + (size_t)M_ * H_);     // [B,CHUNKS,H]
  float* chunkQ = chunkP + (size_t)B_ * CHUNKS * H_;  // [B,CHUNKS,H]
  float* hstate = chunkQ + (size_t)B_ * CHUNKS * H_;  // [B,CHUNKS,H]
  uint*  bar    = (uint*)(hstate + (size_t)B_ * CHUNKS * H_);
  const size_t ws_need = (size_t)((char*)(bar + 1) - (char*)d_ws);

  gemm_zh<<<(M_ / 128) * 4, 256, 0, stream>>>(x, whw, whb, wzw, wzb, ab);

  bool done = false;
  if (ws_size >= ws_need) {
    hipMemsetAsync(bar, 0, sizeof(uint), stream);
    const uint* ab_c = ab;
    void* cargs[7] = {(void*)&ab_c, (void*)&h0, (void*)&chunkP,
                      (void*)&chunkQ, (void*)&hstate, (void*)&out,
                      (void*)&bar};
    hipError_t err = hipLaunchCooperativeKernel(
        scan_fused, dim3(GRID_FUSED), dim3(256), cargs, 0, stream);
    done = (err == hipSuccess);
  }
  if (!done) {
    // Fallback: original 3-kernel scan path.
    scan_phaseA<<<dim3(CHUNKS, B_), 256, 0, stream>>>(ab, chunkP, chunkQ);
    scan_phaseB<<<B_, 256, 0, stream>>>(h0, chunkP, chunkQ, hstate);
    scan_phaseC<<<dim3(CHUNKS, B_), 256, 0, stream>>>(ab, hstate, out);
  }
}

// Round 3
// 181.928 us; speedup vs baseline: 3.2248x; 3.1162x over previous
//
#include <hip/hip_runtime.h>
#include <math.h>

// MinGRU: B=8, S=8192, D=256, H=256, fp32 in/out.
//   K1 gemm_zh : bf16-MFMA dual GEMM (z,h) + sigmoid epilogue + FUSED
//                phase-A: per-chunk (P,Q) composed in-register from the
//                packed bf16 a,b (wave-half == one 64-step chunk) via
//                ordered shfl_xor butterfly. Writes packed ab + chunkPQ.
//   K2 phaseB  : sequential scan over chunk summaries (float2, batch-16).
//   K3 phaseC  : replay; 1 block/chunk, 1 ch/thread, batch-16, fp32 out.
// R1/R2 lesson: register-resident fused scan across a grid sync always
// spills (VGPR pinned at 64, +50MiB scratch writes, 390-414us). No coop.

constexpr int B_ = 8;
constexpr int S_ = 8192;
constexpr int D_ = 256;
constexpr int H_ = 256;
constexpr int M_ = B_ * S_;        // 65536 rows
constexpr int CHUNKS = 128;
constexpr int CLEN = S_ / CHUNKS;  // 64

typedef __attribute__((ext_vector_type(8))) short bf16x8;
typedef __attribute__((ext_vector_type(4))) float f32x4;

// 2 floats -> 2 bf16 (round-to-nearest, ties-away): 2 adds + 1 v_perm.
// lo16 = bf16(f0), hi16 = bf16(f1).
__device__ __forceinline__ uint pack2bf(float f0, float f1) {
  const uint u0 = __float_as_uint(f0) + 0x8000u;
  const uint u1 = __float_as_uint(f1) + 0x8000u;
  return __builtin_amdgcn_perm(u1, u0, 0x07060302u);
}

// ---------------------------------------------------------------- GEMM ----
// Block: 256 thr = 4 waves. Tile: 128 rows x 64 h-channels, both projections.
// LDS rows padded to 72 bf16: conflict-free b128 fragment reads.
// Wave w: rows mb..mb+63 (mb=(w&1)*64 -> exactly one 64-step chunk),
//         channels nb..nb+31 (nb=(w>>1)*32). So each wave owns the full
//         time extent of one chunk for its 32 channels -> phase-A fusable.
__global__ __launch_bounds__(256) void gemm_zh(
    const float* __restrict__ x,
    const float* __restrict__ whw, const float* __restrict__ whb,
    const float* __restrict__ wzw, const float* __restrict__ wzb,
    uint* __restrict__ ab, float2* __restrict__ chunkPQ)
{
  __shared__ ushort xs[128][72];
  __shared__ ushort wzs[64][72];
  __shared__ ushort whs[64][72];

  const int tid = threadIdx.x;
  // XCD swizzle: one 128-row x-panel per XCD group -> x L2-local.
  const int g    = blockIdx.x;
  const int xcd  = g & 7;
  const int loc  = g >> 3;
  const int nt   = loc & 3;
  const int panel = (loc >> 2) * 8 + xcd;
  const int m0 = panel * 128;
  const int n0 = nt * 64;

  const int lane = tid & 63;
  const int w  = tid >> 6;
  const int mb = (w & 1) * 64;
  const int nb = (w >> 1) * 32;
  const int q  = lane >> 4;
  const int cn = lane & 15;

  f32x4 accz[4][2] = {};
  f32x4 acch[4][2] = {};

  for (int k0 = 0; k0 < D_; k0 += 64) {
    __syncthreads();  // WAR guard on LDS reuse
#pragma unroll
    for (int f = 0; f < 8; f++) {  // x: 128 rows x 64 k
      const int idx = tid + 256 * f;
      const int row = idx >> 4, seg = idx & 15;
      float4 v = *(const float4*)(x + (size_t)(m0 + row) * D_ + k0 + seg * 4);
      *(uint2*)&xs[row][seg * 4] =
          make_uint2(pack2bf(v.x, v.y), pack2bf(v.z, v.w));
    }
#pragma unroll
    for (int f = 0; f < 4; f++) {  // weights: 64 rows x 64 k each
      const int idx = tid + 256 * f;
      const int row = idx >> 4, seg = idx & 15;
      float4 vz = *(const float4*)(wzw + (size_t)(n0 + row) * D_ + k0 + seg * 4);
      float4 vh = *(const float4*)(whw + (size_t)(n0 + row) * D_ + k0 + seg * 4);
      *(uint2*)&wzs[row][seg * 4] =
          make_uint2(pack2bf(vz.x, vz.y), pack2bf(vz.z, vz.w));
      *(uint2*)&whs[row][seg * 4] =
          make_uint2(pack2bf(vh.x, vh.y), pack2bf(vh.z, vh.w));
    }
    __syncthreads();
#pragma unroll
    for (int ks = 0; ks < 2; ks++) {
      const int kk = ks * 32 + q * 8;  // A[m=lane&15][k=quad*8+j]
      bf16x8 af[4], bz[2], bh[2];
#pragma unroll
      for (int i = 0; i < 4; i++)
        af[i] = *(const bf16x8*)&xs[mb + i * 16 + cn][kk];
#pragma unroll
      for (int j = 0; j < 2; j++) {
        bz[j] = *(const bf16x8*)&wzs[nb + j * 16 + cn][kk];
        bh[j] = *(const bf16x8*)&whs[nb + j * 16 + cn][kk];
      }
#pragma unroll
      for (int i = 0; i < 4; i++)
#pragma unroll
        for (int j = 0; j < 2; j++) {
          accz[i][j] = __builtin_amdgcn_mfma_f32_16x16x32_bf16(af[i], bz[j], accz[i][j], 0, 0, 0);
          acch[i][j] = __builtin_amdgcn_mfma_f32_16x16x32_bf16(af[i], bh[j], acch[i][j], 0, 0, 0);
        }
    }
  }

  // Chunk identity for this wave (chunks never cross batch: 8192%64==0).
  const int row0 = m0 + mb;
  const int bb2  = row0 >> 13;          // batch
  const int cc   = (row0 & 8191) >> 6;  // chunk within batch

  // Epilogue: C/D col=lane&15, row=quad*4+reg. a=1-z=e*rcp, b=z*h~.
  // t within chunk = i*16 + q*4 + r (ascending in i, q, r).
#pragma unroll
  for (int j = 0; j < 2; j++) {
    const int ch = n0 + nb + j * 16 + cn;
    const float zb = wzb[ch], hb = whb[ch];
    uint u[4][4];
#pragma unroll
    for (int i = 0; i < 4; i++) {
#pragma unroll
      for (int r = 0; r < 4; r++) {
        const int row = m0 + mb + i * 16 + q * 4 + r;
        const float zpre = accz[i][j][r] + zb;
        const float hpre = acch[i][j][r] + hb;
        const float e = __expf(-zpre);
        const float rcp = __builtin_amdgcn_rcpf(1.0f + e);  // z
        const uint pk = pack2bf(e * rcp, hpre * rcp);
        ab[(size_t)row * H_ + ch] = pk;
        u[i][r] = pk;
      }
    }
    // ---- fused phase A: (P,Q) over the 64-step chunk, bit-identical to
    // the old phaseA (composed from the packed bf16 values, fp32 math).
    // Per-lane: 4 steps (r). Butterfly over q (t-order aware). Then i.
    float P[4], Q[4];
#pragma unroll
    for (int i = 0; i < 4; i++) {
      float Pi = 1.f, Qi = 0.f;
#pragma unroll
      for (int r = 0; r < 4; r++) {
        const float a  = __uint_as_float(u[i][r] << 16);
        const float bv = __uint_as_float(u[i][r] & 0xFFFF0000u);
        Qi = fmaf(a, Qi, bv);
        Pi *= a;
      }
      P[i] = Pi; Q[i] = Qi;
    }
    // combine(first,second): P = P1*P2, Q = fma(P2, Q1, Q2).
#pragma unroll
    for (int i = 0; i < 4; i++) {
      {  // partner q^1 (lane^16)
        const float Pp = __shfl_xor(P[i], 16);
        const float Qp = __shfl_xor(Q[i], 16);
        const bool later = (lane & 16) != 0;  // self covers later t
        Q[i] = later ? fmaf(P[i], Qp, Q[i]) : fmaf(Pp, Q[i], Qp);
        P[i] = P[i] * Pp;
      }
      {  // partner q^2 (lane^32)
        const float Pp = __shfl_xor(P[i], 32);
        const float Qp = __shfl_xor(Q[i], 32);
        const bool later = (lane & 32) != 0;
        Q[i] = later ? fmaf(P[i], Qp, Q[i]) : fmaf(Pp, Q[i], Qp);
        P[i] = P[i] * Pp;
      }
    }
    float Pc = P[0], Qc = Q[0];
#pragma unroll
    for (int i = 1; i < 4; i++) {
      Qc = fmaf(P[i], Qc, Q[i]);
      Pc *= P[i];
    }
    if (lane < 16)  // one lane per channel (cn==lane, q==0)
      chunkPQ[((size_t)bb2 * CHUNKS + cc) * H_ + ch] = make_float2(Pc, Qc);
  }
}

// ---------------------------------------------------------------- scans ---
// Phase B: sequential scan over chunk summaries, batch-16 float2 loads.
__global__ __launch_bounds__(256) void scan_phaseB(
    const float* __restrict__ h0in, const float2* __restrict__ pq,
    float* __restrict__ hstate)
{
  const int b = blockIdx.x;
  const int h = threadIdx.x;
  const size_t base = (size_t)b * CHUNKS * H_ + h;
  float hc = h0in[(size_t)b * H_ + h];
  for (int c0 = 0; c0 < CHUNKS; c0 += 16) {
    float2 v[16];
#pragma unroll
    for (int j = 0; j < 16; j++)
      v[j] = pq[base + (size_t)(c0 + j) * H_];
#pragma unroll
    for (int j = 0; j < 16; j++) {
      hstate[base + (size_t)(c0 + j) * H_] = hc;
      hc = fmaf(v[j].x, hc, v[j].y);
    }
  }
}

// Phase C: replay. Block = (chunk, b); thread = 1 channel; batch-16.
__global__ __launch_bounds__(256) void scan_phaseC(
    const uint* __restrict__ ab, const float* __restrict__ hstate,
    float* __restrict__ out)
{
  const int c = blockIdx.x;
  const int b = blockIdx.y;
  const int ch = threadIdx.x;
  size_t base = ((size_t)b * S_ + (size_t)c * CLEN) * H_ + ch;
  float hc = hstate[((size_t)b * CHUNKS + c) * H_ + ch];
#pragma unroll
  for (int t0 = 0; t0 < CLEN; t0 += 16) {
    uint v[16];
#pragma unroll
    for (int j = 0; j < 16; j++)
      v[j] = ab[base + (size_t)(t0 + j) * H_];
#pragma unroll
    for (int j = 0; j < 16; j++) {
      const float a  = __uint_as_float(v[j] << 16);
      const float bb = __uint_as_float(v[j] & 0xFFFF0000u);
      hc = fmaf(a, hc, bb);
      out[base + (size_t)(t0 + j) * H_] = hc;
    }
  }
}

extern "C" void kernel_launch(void* const* d_in, const int* in_sizes, int n_in,
                              void* d_out, int out_size, void* d_ws, size_t ws_size,
                              hipStream_t stream) {
  const float* x   = (const float*)d_in[0];
  const float* h0  = (const float*)d_in[1];
  const float* whw = (const float*)d_in[2];
  const float* whb = (const float*)d_in[3];
  const float* wzw = (const float*)d_in[4];
  const float* wzb = (const float*)d_in[5];
  float* out = (float*)d_out;

  uint*   ab      = (uint*)d_ws;                          // [M,H] packed bf16
  float2* chunkPQ = (float2*)(ab + (size_t)M_ * H_);      // [B,CHUNKS,H]
  float*  hstate  = (float*)(chunkPQ + (size_t)B_ * CHUNKS * H_);  // [B,CHUNKS,H]

  gemm_zh<<<(M_ / 128) * 4, 256, 0, stream>>>(x, whw, whb, wzw, wzb, ab, chunkPQ);
  scan_phaseB<<<B_, 256, 0, stream>>>(h0, (const float2*)chunkPQ, hstate);
  scan_phaseC<<<dim3(CHUNKS, B_), 256, 0, stream>>>(ab, hstate, out);
}